// Round 2
// baseline (677.803 us; speedup 1.0000x reference)
//
#include <hip/hip_runtime.h>

typedef __attribute__((ext_vector_type(8))) _Float16 f16x8;
typedef __attribute__((ext_vector_type(4))) _Float16 f16x4;
typedef __attribute__((ext_vector_type(8))) short bf16x8;
typedef __attribute__((ext_vector_type(4))) float f32x4;
typedef __attribute__((ext_vector_type(4))) unsigned short u16x4;
typedef __attribute__((ext_vector_type(4))) float fx4;

#define D_MODEL 1024
#define N_HEADS 16
#define SEQ 2048
#define TOKENS 4096
#define N_EXP 8
#define EHID 512
#define LO_S 2048.0f
#define INV_LO (1.0f / 2048.0f)

__device__ inline unsigned short f2bf(float f) {
  union { float f; unsigned u; } v; v.f = f;
  unsigned u = v.u;
  return (unsigned short)((u + 0x7FFFu + ((u >> 16) & 1u)) >> 16);
}

__device__ inline void split16(float v, _Float16& h, _Float16& l) {
  h = (_Float16)v;
  l = (_Float16)((v - (float)h) * LO_S);
}

__device__ inline void gload_lds16(const void* g, void* lds) {
  __builtin_amdgcn_global_load_lds((const __attribute__((address_space(1))) void*)g,
                                   (__attribute__((address_space(3))) void*)lds, 16, 0, 0);
}

// ---------------- LayerNorm -> split fp16 planes ----------------
__global__ __launch_bounds__(256) void ln_f16s_kernel(const float* __restrict__ x, const float* __restrict__ g,
                                                      const float* __restrict__ b,
                                                      _Float16* __restrict__ xh, _Float16* __restrict__ xl) {
  int t = blockIdx.x, tid = threadIdx.x;
  const float* row = x + (size_t)t * D_MODEL;
  fx4 v = *(const fx4*)(row + tid * 4);
  float s = v[0] + v[1] + v[2] + v[3];
  float s2 = v[0]*v[0] + v[1]*v[1] + v[2]*v[2] + v[3]*v[3];
  #pragma unroll
  for (int off = 1; off < 64; off <<= 1) { s += __shfl_xor(s, off); s2 += __shfl_xor(s2, off); }
  __shared__ float red[8];
  int wv = tid >> 6, wl = tid & 63;
  if (wl == 0) { red[wv] = s; red[4 + wv] = s2; }
  __syncthreads();
  s = red[0] + red[1] + red[2] + red[3];
  s2 = red[4] + red[5] + red[6] + red[7];
  float mu = s * (1.f / 1024.f);
  float var = s2 * (1.f / 1024.f) - mu * mu;
  float rstd = rsqrtf(var + 1e-5f);
  int kk = tid * 4;
  f16x4 oh, ol;
  #pragma unroll
  for (int c = 0; c < 4; c++) {
    float y = (v[c] - mu) * rstd * g[kk + c] + b[kk + c];
    _Float16 h, lo; split16(y, h, lo);
    oh[c] = h; ol[c] = lo;
  }
  *(f16x4*)(xh + (size_t)t * D_MODEL + kk) = oh;
  *(f16x4*)(xl + (size_t)t * D_MODEL + kk) = ol;
}

// ---------------- LayerNorm -> bf16 (for MoE inputs) ----------------
__global__ __launch_bounds__(256) void ln_bf16_kernel(const float* __restrict__ x, const float* __restrict__ g,
                                                      const float* __restrict__ b, unsigned short* __restrict__ xn) {
  int t = blockIdx.x, tid = threadIdx.x;
  const float* row = x + (size_t)t * D_MODEL;
  fx4 v = *(const fx4*)(row + tid * 4);
  float s = v[0] + v[1] + v[2] + v[3];
  float s2 = v[0]*v[0] + v[1]*v[1] + v[2]*v[2] + v[3]*v[3];
  #pragma unroll
  for (int off = 1; off < 64; off <<= 1) { s += __shfl_xor(s, off); s2 += __shfl_xor(s2, off); }
  __shared__ float red[8];
  int wv = tid >> 6, wl = tid & 63;
  if (wl == 0) { red[wv] = s; red[4 + wv] = s2; }
  __syncthreads();
  s = red[0] + red[1] + red[2] + red[3];
  s2 = red[4] + red[5] + red[6] + red[7];
  float mu = s * (1.f / 1024.f);
  float var = s2 * (1.f / 1024.f) - mu * mu;
  float rstd = rsqrtf(var + 1e-5f);
  int kk = tid * 4;
  u16x4 o;
  #pragma unroll
  for (int c = 0; c < 4; c++) o[c] = f2bf((v[c] - mu) * rstd * g[kk + c] + b[kk + c]);
  *(u16x4*)(xn + (size_t)t * D_MODEL + kk) = o;
}

// ---------------- transpose + split-fp16 cast: dst[C][R] = src[R][C] ----------------
__global__ __launch_bounds__(256) void tcast_f16s_kernel(const float* __restrict__ src,
                                                         _Float16* __restrict__ dh, _Float16* __restrict__ dl,
                                                         int R, int C) {
  __shared__ float tile[32][33];
  size_t mo = (size_t)blockIdx.z * R * C;
  src += mo; dh += mo; dl += mo;
  int c0 = blockIdx.x * 32, r0 = blockIdx.y * 32;
  int tx = threadIdx.x & 31, ty = threadIdx.x >> 5;
  #pragma unroll
  for (int i = 0; i < 4; i++) tile[ty + 8*i][tx] = src[(size_t)(r0 + ty + 8*i) * C + c0 + tx];
  __syncthreads();
  #pragma unroll
  for (int i = 0; i < 4; i++) {
    float v = tile[tx][ty + 8*i];
    _Float16 h, lo; split16(v, h, lo);
    size_t idx = (size_t)(c0 + ty + 8*i) * R + r0 + tx;
    dh[idx] = h; dl[idx] = lo;
  }
}

// ---------------- transpose + bf16 cast (MoE weights) ----------------
__global__ __launch_bounds__(256) void tcast_bf16_kernel(const float* __restrict__ src, unsigned short* __restrict__ dst,
                                                         int R, int C) {
  __shared__ float tile[32][33];
  size_t mo = (size_t)blockIdx.z * R * C;
  src += mo; dst += mo;
  int c0 = blockIdx.x * 32, r0 = blockIdx.y * 32;
  int tx = threadIdx.x & 31, ty = threadIdx.x >> 5;
  #pragma unroll
  for (int i = 0; i < 4; i++) tile[ty + 8*i][tx] = src[(size_t)(r0 + ty + 8*i) * C + c0 + tx];
  __syncthreads();
  #pragma unroll
  for (int i = 0; i < 4; i++) dst[(size_t)(c0 + ty + 8*i) * R + r0 + tx] = f2bf(tile[tx][ty + 8*i]);
}

// ---------------- split-fp16 128x128 GEMM core ----------------
// A planes [M][K], B^T planes [N][K]; LDS ls: Ah@0, Al@4096, Bh@8192, Bl@12288 (elements)
__device__ inline void gemm128s(const _Float16* __restrict__ Ah, const _Float16* __restrict__ Al,
                                const _Float16* __restrict__ Bh, const _Float16* __restrict__ Bl,
                                int lda, int ldb, int K, int bm, int bn,
                                _Float16* ls, f32x4 (&acc)[4][4], f32x4 (&accx)[4][4]) {
  const int tid = threadIdx.x, w = tid >> 6, l = tid & 63, lr = l & 15, lg = l >> 4;
  const int wr = (w >> 1) * 64, wc = (w & 1) * 64;
  int Ea0 = tid * 8, Ea1 = (256 + tid) * 8;
  int ra0 = Ea0 >> 5, ca0 = Ea0 & 31, ra1 = Ea1 >> 5, ca1 = Ea1 & 31;
  const _Float16* gAh0 = Ah + (size_t)(bm + ra0) * lda + ca0;
  const _Float16* gAh1 = Ah + (size_t)(bm + ra1) * lda + ca1;
  const _Float16* gAl0 = Al + (size_t)(bm + ra0) * lda + ca0;
  const _Float16* gAl1 = Al + (size_t)(bm + ra1) * lda + ca1;
  const _Float16* gBh0 = Bh + (size_t)(bn + ra0) * ldb + ca0;
  const _Float16* gBh1 = Bh + (size_t)(bn + ra1) * ldb + ca1;
  const _Float16* gBl0 = Bl + (size_t)(bn + ra0) * ldb + ca0;
  const _Float16* gBl1 = Bl + (size_t)(bn + ra1) * ldb + ca1;
  char* base = (char*)ls;
  char* dAh0 = base + w * 1024;          char* dAh1 = base + 4096 + w * 1024;
  char* dAl0 = base + 8192 + w * 1024;   char* dAl1 = base + 12288 + w * 1024;
  char* dBh0 = base + 16384 + w * 1024;  char* dBh1 = base + 20480 + w * 1024;
  char* dBl0 = base + 24576 + w * 1024;  char* dBl1 = base + 28672 + w * 1024;
  for (int ko = 0; ko < K; ko += 32) {
    gload_lds16(gAh0 + ko, dAh0); gload_lds16(gAh1 + ko, dAh1);
    gload_lds16(gAl0 + ko, dAl0); gload_lds16(gAl1 + ko, dAl1);
    gload_lds16(gBh0 + ko, dBh0); gload_lds16(gBh1 + ko, dBh1);
    gload_lds16(gBl0 + ko, dBl0); gload_lds16(gBl1 + ko, dBl1);
    __syncthreads();
    f16x8 ah[4], al4[4], bh4[4], bl4[4];
    #pragma unroll
    for (int m = 0; m < 4; m++) {
      ah[m]  = *(const f16x8*)(ls + (wr + m*16 + lr) * 32 + lg * 8);
      al4[m] = *(const f16x8*)(ls + 4096 + (wr + m*16 + lr) * 32 + lg * 8);
    }
    #pragma unroll
    for (int n = 0; n < 4; n++) {
      bh4[n] = *(const f16x8*)(ls + 8192 + (wc + n*16 + lr) * 32 + lg * 8);
      bl4[n] = *(const f16x8*)(ls + 12288 + (wc + n*16 + lr) * 32 + lg * 8);
    }
    #pragma unroll
    for (int m = 0; m < 4; m++)
      #pragma unroll
      for (int n = 0; n < 4; n++) {
        acc[m][n]  = __builtin_amdgcn_mfma_f32_16x16x32_f16(ah[m], bh4[n], acc[m][n], 0, 0, 0);
        accx[m][n] = __builtin_amdgcn_mfma_f32_16x16x32_f16(ah[m], bl4[n], accx[m][n], 0, 0, 0);
        accx[m][n] = __builtin_amdgcn_mfma_f32_16x16x32_f16(al4[m], bh4[n], accx[m][n], 0, 0, 0);
      }
    __syncthreads();
  }
}

// ---------------- QKV GEMM -> q,k [BH][S][64] hi/lo, vT [BH][64][S] hi/lo ----------------
__global__ __launch_bounds__(256) void gemm_qkv_kernel(const _Float16* __restrict__ xh, const _Float16* __restrict__ xl,
                                                       const _Float16* __restrict__ Wh, const _Float16* __restrict__ Wl,
                                                       _Float16* __restrict__ qh, _Float16* __restrict__ ql,
                                                       _Float16* __restrict__ kh, _Float16* __restrict__ kl,
                                                       _Float16* __restrict__ vh, _Float16* __restrict__ vl) {
  __shared__ _Float16 ls[16384];
  f32x4 acc[4][4] = {}, accx[4][4] = {};
  int bm = blockIdx.x * 128, bn = blockIdx.y * 128;
  gemm128s(xh, xl, Wh, Wl, 1024, 1024, 1024, bm, bn, ls, acc, accx);
  const int tid = threadIdx.x, w = tid >> 6, l = tid & 63, lr = l & 15, lg = l >> 4;
  const int wr = (w >> 1) * 64, wc = (w & 1) * 64;
  #pragma unroll
  for (int m = 0; m < 4; m++) {
    int row0 = bm + wr + m * 16 + lg * 4;
    #pragma unroll
    for (int n = 0; n < 4; n++) {
      int col = bn + wc + n * 16 + lr;
      int mat = col >> 10;
      int c = col & 1023, h = c >> 6, d = c & 63;
      if (mat == 2) {
        int bb = row0 >> 11, ss = row0 & 2047;
        f16x4 ph, pl;
        #pragma unroll
        for (int j = 0; j < 4; j++) {
          float v = acc[m][n][j] + accx[m][n][j] * INV_LO;
          _Float16 hh, ll; split16(v, hh, ll);
          ph[j] = hh; pl[j] = ll;
        }
        size_t idx = ((size_t)(bb * N_HEADS + h) * 64 + d) * SEQ + ss;
        *(f16x4*)(vh + idx) = ph;
        *(f16x4*)(vl + idx) = pl;
      } else {
        _Float16* dsth = (mat == 0) ? qh : kh;
        _Float16* dstl = (mat == 0) ? ql : kl;
        #pragma unroll
        for (int j = 0; j < 4; j++) {
          float v = acc[m][n][j] + accx[m][n][j] * INV_LO;
          _Float16 hh, ll; split16(v, hh, ll);
          int t = row0 + j, bb = t >> 11, ss = t & 2047;
          size_t idx = ((size_t)(bb * N_HEADS + h) * SEQ + ss) * 64 + d;
          dsth[idx] = hh; dstl[idx] = ll;
        }
      }
    }
  }
}

// ---------------- Flash attention (split fp16), KVBLK=32 ----------------
#define SD 72
#define SVD 40
__global__ __launch_bounds__(256) void flash_kernel(const _Float16* __restrict__ qhp, const _Float16* __restrict__ qlp,
                                                    const _Float16* __restrict__ khp, const _Float16* __restrict__ klp,
                                                    const _Float16* __restrict__ vhp, const _Float16* __restrict__ vlp,
                                                    _Float16* __restrict__ oh, _Float16* __restrict__ ol) {
  __shared__ _Float16 lsKh[32 * SD], lsKl[32 * SD];
  __shared__ _Float16 lsVh[64 * SVD], lsVl[64 * SVD];
  __shared__ _Float16 lsPh[4][32 * SVD], lsPl[4][32 * SVD];
  int bh = blockIdx.y, qt = blockIdx.x;
  int tid = threadIdx.x, w = tid >> 6, l = tid & 63, lr = l & 15, lg = l >> 4;
  const _Float16* qhb = qhp + (size_t)bh * SEQ * 64;
  const _Float16* qlb = qlp + (size_t)bh * SEQ * 64;
  const _Float16* khb = khp + (size_t)bh * SEQ * 64;
  const _Float16* klb = klp + (size_t)bh * SEQ * 64;
  const _Float16* vhb = vhp + (size_t)bh * 64 * SEQ;
  const _Float16* vlb = vlp + (size_t)bh * 64 * SEQ;
  int q0 = qt * 128 + w * 32;
  f16x8 qfh[2][2], qfl[2][2];
  #pragma unroll
  for (int nf = 0; nf < 2; nf++)
    #pragma unroll
    for (int ks = 0; ks < 2; ks++) {
      size_t idx = (size_t)(q0 + nf*16 + lr) * 64 + ks * 32 + lg * 8;
      qfh[nf][ks] = *(const f16x8*)(qhb + idx);
      qfl[nf][ks] = *(const f16x8*)(qlb + idx);
    }

  f32x4 acc[4][2] = {}, accx[4][2] = {};
  float mst[2] = {-1e30f, -1e30f};
  float lst[2] = {0.f, 0.f};

  int e8 = tid * 8;
  int kr_ = e8 >> 6, kc_ = e8 & 63;   // K tile: 32 rows x 64 cols
  int vr_ = e8 >> 5, vc_ = e8 & 31;   // V tile: 64 rows x 32 cols

  for (int kv0 = 0; kv0 < SEQ; kv0 += 32) {
    fx4 a0 = *(const fx4*)(khb + (size_t)(kv0 + kr_) * 64 + kc_);
    fx4 a1 = *(const fx4*)(klb + (size_t)(kv0 + kr_) * 64 + kc_);
    fx4 a2 = *(const fx4*)(vhb + (size_t)vr_ * SEQ + kv0 + vc_);
    fx4 a3 = *(const fx4*)(vlb + (size_t)vr_ * SEQ + kv0 + vc_);
    __syncthreads();
    *(fx4*)(lsKh + kr_ * SD + kc_) = a0;
    *(fx4*)(lsKl + kr_ * SD + kc_) = a1;
    *(fx4*)(lsVh + vr_ * SVD + vc_) = a2;
    *(fx4*)(lsVl + vr_ * SVD + vc_) = a3;
    __syncthreads();

    f32x4 shh[2][2] = {}, sx[2][2] = {};
    #pragma unroll
    for (int ks = 0; ks < 2; ks++) {
      f16x8 kfh[2], kfl[2];
      #pragma unroll
      for (int m = 0; m < 2; m++) {
        kfh[m] = *(const f16x8*)(lsKh + (m*16 + lr) * SD + ks * 32 + lg * 8);
        kfl[m] = *(const f16x8*)(lsKl + (m*16 + lr) * SD + ks * 32 + lg * 8);
      }
      #pragma unroll
      for (int m = 0; m < 2; m++)
        #pragma unroll
        for (int nf = 0; nf < 2; nf++) {
          shh[m][nf] = __builtin_amdgcn_mfma_f32_16x16x32_f16(kfh[m], qfh[nf][ks], shh[m][nf], 0, 0, 0);
          sx[m][nf]  = __builtin_amdgcn_mfma_f32_16x16x32_f16(kfh[m], qfl[nf][ks], sx[m][nf], 0, 0, 0);
          sx[m][nf]  = __builtin_amdgcn_mfma_f32_16x16x32_f16(kfl[m], qfh[nf][ks], sx[m][nf], 0, 0, 0);
        }
    }

    #pragma unroll
    for (int nf = 0; nf < 2; nf++) {
      float tm = -3e38f;
      #pragma unroll
      for (int m = 0; m < 2; m++)
        #pragma unroll
        for (int j = 0; j < 4; j++) {
          float sc = (shh[m][nf][j] + sx[m][nf][j] * INV_LO) * 0.125f;
          shh[m][nf][j] = sc;
          tm = fmaxf(tm, sc);
        }
      tm = fmaxf(tm, __shfl_xor(tm, 16));
      tm = fmaxf(tm, __shfl_xor(tm, 32));
      float mnew = fmaxf(mst[nf], tm);
      float corr = __expf(mst[nf] - mnew);
      float psum = 0.f;
      #pragma unroll
      for (int m = 0; m < 2; m++)
        #pragma unroll
        for (int j = 0; j < 4; j++) {
          float p = __expf(shh[m][nf][j] - mnew);
          shh[m][nf][j] = p;
          psum += p;
        }
      psum += __shfl_xor(psum, 16);
      psum += __shfl_xor(psum, 32);
      lst[nf] = lst[nf] * corr + psum;
      mst[nf] = mnew;
      #pragma unroll
      for (int m2 = 0; m2 < 4; m2++)
        #pragma unroll
        for (int j = 0; j < 4; j++) { acc[m2][nf][j] *= corr; accx[m2][nf][j] *= corr; }
      #pragma unroll
      for (int m = 0; m < 2; m++) {
        f16x4 ph, pl;
        #pragma unroll
        for (int j = 0; j < 4; j++) {
          _Float16 hh, ll; split16(shh[m][nf][j], hh, ll);
          ph[j] = hh; pl[j] = ll;
        }
        *(f16x4*)(&lsPh[w][(nf*16 + lr) * SVD + m * 16 + lg * 4]) = ph;
        *(f16x4*)(&lsPl[w][(nf*16 + lr) * SVD + m * 16 + lg * 4]) = pl;
      }
    }

    f16x8 vfh[4], vfl[4], pfh[2], pfl[2];
    #pragma unroll
    for (int m2 = 0; m2 < 4; m2++) {
      vfh[m2] = *(const f16x8*)(lsVh + (m2*16 + lr) * SVD + lg * 8);
      vfl[m2] = *(const f16x8*)(lsVl + (m2*16 + lr) * SVD + lg * 8);
    }
    #pragma unroll
    for (int nf = 0; nf < 2; nf++) {
      pfh[nf] = *(const f16x8*)(&lsPh[w][(nf*16 + lr) * SVD + lg * 8]);
      pfl[nf] = *(const f16x8*)(&lsPl[w][(nf*16 + lr) * SVD + lg * 8]);
    }
    #pragma unroll
    for (int m2 = 0; m2 < 4; m2++)
      #pragma unroll
      for (int nf = 0; nf < 2; nf++) {
        acc[m2][nf]  = __builtin_amdgcn_mfma_f32_16x16x32_f16(vfh[m2], pfh[nf], acc[m2][nf], 0, 0, 0);
        accx[m2][nf] = __builtin_amdgcn_mfma_f32_16x16x32_f16(vfh[m2], pfl[nf], accx[m2][nf], 0, 0, 0);
        accx[m2][nf] = __builtin_amdgcn_mfma_f32_16x16x32_f16(vfl[m2], pfh[nf], accx[m2][nf], 0, 0, 0);
      }
  }

  int b = bh >> 4, h = bh & 15;
  #pragma unroll
  for (int nf = 0; nf < 2; nf++) {
    float inv = 1.f / lst[nf];
    int qq = q0 + nf * 16 + lr;
    int t = b * SEQ + qq;
    #pragma unroll
    for (int m2 = 0; m2 < 4; m2++) {
      f16x4 ph, pl;
      #pragma unroll
      for (int j = 0; j < 4; j++) {
        float o = (acc[m2][nf][j] + accx[m2][nf][j] * INV_LO) * inv;
        _Float16 hh, ll; split16(o, hh, ll);
        ph[j] = hh; pl[j] = ll;
      }
      size_t idx = (size_t)t * D_MODEL + h * 64 + m2 * 16 + lg * 4;
      *(f16x4*)(oh + idx) = ph;
      *(f16x4*)(ol + idx) = pl;
    }
  }
}

// ---------------- O-proj GEMM + residual -> d_out (fp32) ----------------
__global__ __launch_bounds__(256) void gemm_oproj_kernel(const _Float16* __restrict__ ah, const _Float16* __restrict__ al,
                                                         const _Float16* __restrict__ Wh, const _Float16* __restrict__ Wl,
                                                         const float* __restrict__ x, float* __restrict__ out) {
  __shared__ _Float16 ls[16384];
  f32x4 acc[4][4] = {}, accx[4][4] = {};
  int bm = blockIdx.x * 128, bn = blockIdx.y * 128;
  gemm128s(ah, al, Wh, Wl, 1024, 1024, 1024, bm, bn, ls, acc, accx);
  const int tid = threadIdx.x, w = tid >> 6, l = tid & 63, lr = l & 15, lg = l >> 4;
  const int wr = (w >> 1) * 64, wc = (w & 1) * 64;
  #pragma unroll
  for (int m = 0; m < 4; m++) {
    int row0 = bm + wr + m * 16 + lg * 4;
    #pragma unroll
    for (int n = 0; n < 4; n++) {
      int col = bn + wc + n * 16 + lr;
      #pragma unroll
      for (int j = 0; j < 4; j++) {
        size_t idx = (size_t)(row0 + j) * D_MODEL + col;
        out[idx] = (acc[m][n][j] + accx[m][n][j] * INV_LO) + x[idx];
      }
    }
  }
}

// ---------------- fused LN2 + gate + top2 (fp32) ----------------
__global__ __launch_bounds__(256) void gate_kernel(const float* __restrict__ x1, const float* __restrict__ Wg,
                                                   const float* __restrict__ g2, const float* __restrict__ b2,
                                                   int* __restrict__ cnt, int* __restrict__ topi,
                                                   float* __restrict__ topw) {
  int t = blockIdx.x * 4 + (threadIdx.x >> 6);
  int l = threadIdx.x & 63;
  const float* row = x1 + (size_t)t * D_MODEL;
  fx4 v[4];
  float s = 0.f, s2 = 0.f;
  #pragma unroll
  for (int i = 0; i < 4; i++) {
    v[i] = *(const fx4*)(row + l * 16 + i * 4);
    #pragma unroll
    for (int c = 0; c < 4; c++) { s += v[i][c]; s2 += v[i][c] * v[i][c]; }
  }
  #pragma unroll
  for (int off = 1; off < 64; off <<= 1) { s += __shfl_xor(s, off); s2 += __shfl_xor(s2, off); }
  float mu = s * (1.f / 1024.f);
  float var = s2 * (1.f / 1024.f) - mu * mu;
  float rstd = rsqrtf(var + 1e-5f);
  float a8[8] = {0,0,0,0,0,0,0,0};
  #pragma unroll
  for (int i = 0; i < 4; i++)
    #pragma unroll
    for (int c = 0; c < 4; c++) {
      int kk = l * 16 + i * 4 + c;
      float xv = (v[i][c] - mu) * rstd * g2[kk] + b2[kk];
      const float* wr_ = Wg + (size_t)kk * 8;
      fx4 wa = *(const fx4*)wr_;
      fx4 wb = *(const fx4*)(wr_ + 4);
      a8[0] += xv * wa[0]; a8[1] += xv * wa[1]; a8[2] += xv * wa[2]; a8[3] += xv * wa[3];
      a8[4] += xv * wb[0]; a8[5] += xv * wb[1]; a8[6] += xv * wb[2]; a8[7] += xv * wb[3];
    }
  #pragma unroll
  for (int e = 0; e < 8; e++)
    #pragma unroll
    for (int off = 1; off < 64; off <<= 1) a8[e] += __shfl_xor(a8[e], off);
  if (l == 0) {
    int i0 = 0; float v0 = a8[0];
    #pragma unroll
    for (int e = 1; e < 8; e++) if (a8[e] > v0) { v0 = a8[e]; i0 = e; }
    int i1 = -1; float v1 = -3.4e38f;
    #pragma unroll
    for (int e = 0; e < 8; e++) if (e != i0 && a8[e] > v1) { v1 = a8[e]; i1 = e; }
    float p0 = 1.f / (1.f + __expf(v1 - v0));
    topi[t * 2] = i0; topi[t * 2 + 1] = i1;
    topw[t * 2] = p0; topw[t * 2 + 1] = 1.f - p0;
    atomicAdd(&cnt[i0], 1); atomicAdd(&cnt[i1], 1);
  }
}

__global__ void init_kernel(int* cnt, int* perm, float* pw) {
  int i = blockIdx.x * 256 + threadIdx.x;
  if (i < 8) cnt[i] = 0;
  if (i < 8448) { perm[i] = 0; pw[i] = 0.f; }
}

__global__ void offsets_kernel(const int* __restrict__ cnt, int* __restrict__ poff) {
  if (threadIdx.x == 0) {
    int a = 0;
    for (int e = 0; e < 8; e++) { poff[e] = a; a += ((cnt[e] + 31) >> 5) << 5; }
  }
}

// stable partition of the 8192 (token,k) assignments by expert -> deterministic
__global__ __launch_bounds__(256) void scatter_kernel(const int* __restrict__ topi, const float* __restrict__ topw,
                                                      const int* __restrict__ poff, int* __restrict__ perm,
                                                      float* __restrict__ pw) {
  int e = blockIdx.x, tid = threadIdx.x;
  __shared__ int basesh;
  __shared__ int wsum[4];
  if (tid == 0) basesh = poff[e];
  __syncthreads();
  for (int seg = 0; seg < 8192; seg += 256) {
    int a = seg + tid;
    int match = (topi[a] == e) ? 1 : 0;
    unsigned long long bal = __ballot(match);
    int wl = tid & 63, wv = tid >> 6;
    int lanepre = __popcll(bal & ((1ULL << wl) - 1ULL));
    if (wl == 0) wsum[wv] = __popcll(bal);
    __syncthreads();
    int wpre = 0;
    for (int i = 0; i < wv; i++) wpre += wsum[i];
    int total = wsum[0] + wsum[1] + wsum[2] + wsum[3];
    if (match) {
      int pos = basesh + wpre + lanepre;
      perm[pos] = a >> 1;
      pw[pos] = topw[a];
    }
    __syncthreads();
    if (tid == 0) basesh += total;
    __syncthreads();
  }
}

// ---------------- MoE FFN: 32-token tile, fused W1->relu->W2, atomicAdd into out ----------------
__global__ __launch_bounds__(256) void moe_ffn_kernel(const unsigned short* __restrict__ xn2,
                                                      const unsigned short* __restrict__ W1T,
                                                      const unsigned short* __restrict__ W2T,
                                                      const int* __restrict__ cnt, const int* __restrict__ poff,
                                                      const int* __restrict__ perm, const float* __restrict__ pw,
                                                      float* __restrict__ out) {
  int bid = blockIdx.x;
  int e = -1, lt = bid;
  for (int i = 0; i < 8; i++) {
    int nt = (cnt[i] + 31) >> 5;
    if (lt < nt) { e = i; break; }
    lt -= nt;
  }
  if (e < 0) return;
  int slot0 = poff[e] + lt * 32;

  __shared__ int t_sh[32];
  __shared__ float w_sh[32];
  __shared__ unsigned short lsX[32 * 32];
  __shared__ unsigned short hsh[32 * 520];
  int tid = threadIdx.x, w = tid >> 6, l = tid & 63, lr = l & 15, lg = l >> 4;
  if (tid < 32) { t_sh[tid] = perm[slot0 + tid]; w_sh[tid] = pw[slot0 + tid]; }
  __syncthreads();

  int Xr = (tid * 8) >> 5, Xc = (tid * 8) & 31;
  const unsigned short* gX = xn2 + (size_t)(tid < 128 ? t_sh[Xr] : 0) * D_MODEL + Xc;
  const unsigned short* W1e = W1T + (size_t)e * EHID * D_MODEL;
  const unsigned short* W2e = W2T + (size_t)e * D_MODEL * EHID;

  f32x4 acc[2][8] = {};
  for (int ko = 0; ko < D_MODEL; ko += 32) {
    if (tid < 128) gload_lds16(gX + ko, (char*)lsX + w * 1024);
    __syncthreads();
    bf16x8 a[2];
    #pragma unroll
    for (int m = 0; m < 2; m++) a[m] = *(const bf16x8*)(lsX + (m*16 + lr) * 32 + lg * 8);
    #pragma unroll
    for (int n = 0; n < 8; n++) {
      bf16x8 bb = *(const bf16x8*)(W1e + (size_t)(w * 128 + n * 16 + lr) * D_MODEL + ko + lg * 8);
      #pragma unroll
      for (int m = 0; m < 2; m++)
        acc[m][n] = __builtin_amdgcn_mfma_f32_16x16x32_bf16(a[m], bb, acc[m][n], 0, 0, 0);
    }
    __syncthreads();
  }
  #pragma unroll
  for (int m = 0; m < 2; m++)
    #pragma unroll
    for (int n = 0; n < 8; n++)
      #pragma unroll
      for (int j = 0; j < 4; j++)
        hsh[(m*16 + lg*4 + j) * 520 + w * 128 + n * 16 + lr] = f2bf(fmaxf(acc[m][n][j], 0.f));
  __syncthreads();

  for (int p = 0; p < 2; p++) {
    f32x4 acc2[2][8] = {};
    for (int k2 = 0; k2 < EHID; k2 += 32) {
      bf16x8 a2[2];
      #pragma unroll
      for (int m = 0; m < 2; m++) a2[m] = *(const bf16x8*)(hsh + (m*16 + lr) * 520 + k2 + lg * 8);
      #pragma unroll
      for (int n = 0; n < 8; n++) {
        int ycol = w * 256 + p * 128 + n * 16 + lr;
        bf16x8 bb = *(const bf16x8*)(W2e + (size_t)ycol * EHID + k2 + lg * 8);
        #pragma unroll
        for (int m = 0; m < 2; m++)
          acc2[m][n] = __builtin_amdgcn_mfma_f32_16x16x32_bf16(a2[m], bb, acc2[m][n], 0, 0, 0);
      }
    }
    #pragma unroll
    for (int m = 0; m < 2; m++)
      #pragma unroll
      for (int j = 0; j < 4; j++) {
        int r = m * 16 + lg * 4 + j;
        int t = t_sh[r];
        float wt = w_sh[r];
        if (wt != 0.f) {
          #pragma unroll
          for (int n = 0; n < 8; n++)
            atomicAdd(&out[(size_t)t * D_MODEL + w * 256 + p * 128 + n * 16 + lr], acc2[m][n][j] * wt);
        }
      }
  }
}

// ---------------- launcher ----------------
#define MB (1u << 20)
extern "C" void kernel_launch(void* const* d_in, const int* in_sizes, int n_in,
                              void* d_out, int out_size, void* d_ws, size_t ws_size,
                              hipStream_t stream) {
  const float* x  = (const float*)d_in[0];
  const float* Wq = (const float*)d_in[1];
  const float* Wk = (const float*)d_in[2];
  const float* Wv = (const float*)d_in[3];
  const float* Wo = (const float*)d_in[4];
  const float* g1 = (const float*)d_in[5];
  const float* b1 = (const float*)d_in[6];
  const float* g2 = (const float*)d_in[7];
  const float* b2 = (const float*)d_in[8];
  const float* Wg = (const float*)d_in[9];
  const float* W1 = (const float*)d_in[10];
  const float* W2 = (const float*)d_in[11];
  float* out = (float*)d_out;

  char* ws = (char*)d_ws;
  _Float16* xn1h = (_Float16*)(ws + 0*MB);     // later aliased as attn hi plane
  _Float16* xn1l = (_Float16*)(ws + 8*MB);     // later aliased as attn lo plane
  _Float16* Wqkh = (_Float16*)(ws + 16*MB);
  _Float16* Wqkl = (_Float16*)(ws + 22*MB);
  _Float16* Woh  = (_Float16*)(ws + 28*MB);
  _Float16* Wol  = (_Float16*)(ws + 30*MB);
  _Float16* qhb  = (_Float16*)(ws + 32*MB);
  _Float16* qlb  = (_Float16*)(ws + 40*MB);
  _Float16* khb  = (_Float16*)(ws + 48*MB);
  _Float16* klb  = (_Float16*)(ws + 56*MB);
  _Float16* vhb  = (_Float16*)(ws + 64*MB);
  _Float16* vlb  = (_Float16*)(ws + 72*MB);
  unsigned short* xn2 = (unsigned short*)(ws + 80*MB);
  unsigned short* W1T = (unsigned short*)(ws + 88*MB);
  unsigned short* W2T = (unsigned short*)(ws + 96*MB);
  char* misc = ws + 104*MB;
  int*   topi = (int*)(misc);
  float* topw = (float*)(misc + 32768);
  int*   cnt  = (int*)(misc + 65536);
  int*   poff = (int*)(misc + 65568);
  int*   perm = (int*)(misc + 65600);
  float* pwts = (float*)(misc + 99392);
  _Float16* attnh = xn1h;
  _Float16* attnl = xn1l;

  // weight prep + routing init
  tcast_f16s_kernel<<<dim3(32, 32, 1), 256, 0, stream>>>(Wq, Wqkh, Wqkl, 1024, 1024);
  tcast_f16s_kernel<<<dim3(32, 32, 1), 256, 0, stream>>>(Wk, Wqkh + 1048576, Wqkl + 1048576, 1024, 1024);
  tcast_f16s_kernel<<<dim3(32, 32, 1), 256, 0, stream>>>(Wv, Wqkh + 2097152, Wqkl + 2097152, 1024, 1024);
  tcast_f16s_kernel<<<dim3(32, 32, 1), 256, 0, stream>>>(Wo, Woh, Wol, 1024, 1024);
  tcast_bf16_kernel<<<dim3(16, 32, 8), 256, 0, stream>>>(W1, W1T, 1024, 512);
  tcast_bf16_kernel<<<dim3(32, 16, 8), 256, 0, stream>>>(W2, W2T, 512, 1024);
  init_kernel<<<33, 256, 0, stream>>>(cnt, perm, pwts);

  // attention path (split fp16, ~fp32 accuracy)
  ln_f16s_kernel<<<TOKENS, 256, 0, stream>>>(x, g1, b1, xn1h, xn1l);
  gemm_qkv_kernel<<<dim3(32, 24), 256, 0, stream>>>(xn1h, xn1l, Wqkh, Wqkl, qhb, qlb, khb, klb, vhb, vlb);
  flash_kernel<<<dim3(16, 32), 256, 0, stream>>>(qhb, qlb, khb, klb, vhb, vlb, attnh, attnl);
  gemm_oproj_kernel<<<dim3(32, 8), 256, 0, stream>>>(attnh, attnl, Woh, Wol, x, out);

  // MoE path
  ln_bf16_kernel<<<TOKENS, 256, 0, stream>>>(out, g2, b2, xn2);
  gate_kernel<<<1024, 256, 0, stream>>>(out, Wg, g2, b2, cnt, topi, topw);
  offsets_kernel<<<1, 64, 0, stream>>>(cnt, poff);
  scatter_kernel<<<8, 256, 0, stream>>>(topi, topw, poff, perm, pwts);
  moe_ffn_kernel<<<264, 256, 0, stream>>>(xn2, W1T, W2T, cnt, poff, perm, pwts, out);

  (void)in_sizes; (void)n_in; (void)out_size; (void)ws_size;
}